// Round 4
// baseline (819.738 us; speedup 1.0000x reference)
//
#include <hip/hip_runtime.h>

// Problem constants (match reference)
#define B_N 2048
#define C_N 64
#define D_N 1024
// K_ACTIVE=4, N_POS=12, N_NEG_PER=20
#define MARGIN_C 0.15f
#define INV_TEMP (1.0f / 0.07f)

__device__ __forceinline__ float wred(float v) {
#pragma unroll
    for (int off = 32; off > 0; off >>= 1) v += __shfl_xor(v, off, 64);
    return v;
}

// ROUND 4 = MEASUREMENT ROUND: loss_kernel is byte-identical to round 3 but
// launched TWICE (idempotent, deterministic) — the dur_us delta vs round 3
// (699.8 us) measures one loss_kernel duration exactly.
__global__ __launch_bounds__(256, 4)
void loss_kernel(const float* __restrict__ pred,
                 const int*   __restrict__ lab,
                 const float* __restrict__ emb,
                 const float* __restrict__ cpos,
                 const float* __restrict__ conn,
                 float* __restrict__ partial)
{
    __shared__ float4 s_frag4[1024];  // 16 KB: the 4 active rows, staged once
    __shared__ float  s_p[64];
    __shared__ int    s_inact[60];
    __shared__ float  s_dots[64][4];  // dots[c][j] = dot(emb_c, emb_act_j) raw
    __shared__ float  s_nsq[64];      // squared norms
    __shared__ float  s_pos[192];     // 64 x 3 channel positions
    __shared__ float  s_part[6];

    const int tid  = threadIdx.x;
    const int w    = tid >> 6;
    const int lane = tid & 63;
    const int b    = blockIdx.x;

    // ---- preamble: fully parallel, no serial tid==0 chain ----
    const float p_lane = pred[b * 64 + lane];   // every wave loads (L1-shared)
    const int   l_lane = lab[b * 64 + lane];
    if (tid >= 64 && tid < 256) s_pos[tid - 64] = cpos[tid - 64];

    const unsigned long long mask = __ballot(l_lane != 0);   // wave-uniform, same in all waves
    unsigned long long mtmp = mask;
    int act[4];
#pragma unroll
    for (int j = 0; j < 4; j++) { act[j] = __builtin_ctzll(mtmp); mtmp &= mtmp - 1; }

    // cooperative staging of the 4 active rows into LDS (4 KB per row, coalesced)
    const float4* base = (const float4*)emb + (long)b * 64 * 256;
#pragma unroll
    for (int k = 0; k < 4; k++) s_frag4[k * 256 + tid] = base[act[k] * 256 + tid];

    if (w == 0) {
        s_p[lane] = p_lane;
        if (!((mask >> lane) & 1ull)) {
            int r = __popcll(~mask & ((1ull << lane) - 1ull));  // rank among inactive
            s_inact[r] = lane;
        }
    }
    __syncthreads();

    // ---- fragments LDS -> registers ----
    float4 frag[4][4];
#pragma unroll
    for (int j = 0; j < 4; j++)
#pragma unroll
        for (int t = 0; t < 4; t++) frag[j][t] = s_frag4[j * 256 + lane + 64 * t];

    // ---- main stream: wave w owns rows c = w + 4*i, one-row-ahead prefetch ----
    auto compute_row = [&](const float4* buf, int c) {
        float a0 = 0.f, a1 = 0.f, a2 = 0.f, a3 = 0.f, ns = 0.f;
#pragma unroll
        for (int t = 0; t < 4; t++) {
            float4 u = buf[t];
            ns += u.x * u.x + u.y * u.y + u.z * u.z + u.w * u.w;
            a0 += u.x * frag[0][t].x + u.y * frag[0][t].y + u.z * frag[0][t].z + u.w * frag[0][t].w;
            a1 += u.x * frag[1][t].x + u.y * frag[1][t].y + u.z * frag[1][t].z + u.w * frag[1][t].w;
            a2 += u.x * frag[2][t].x + u.y * frag[2][t].y + u.z * frag[2][t].z + u.w * frag[2][t].w;
            a3 += u.x * frag[3][t].x + u.y * frag[3][t].y + u.z * frag[3][t].z + u.w * frag[3][t].w;
        }
#pragma unroll
        for (int off = 32; off > 0; off >>= 1) {
            a0 += __shfl_xor(a0, off, 64); a1 += __shfl_xor(a1, off, 64);
            a2 += __shfl_xor(a2, off, 64); a3 += __shfl_xor(a3, off, 64);
            ns += __shfl_xor(ns, off, 64);
        }
        if (lane == 0) {
            s_dots[c][0] = a0; s_dots[c][1] = a1; s_dots[c][2] = a2; s_dots[c][3] = a3;
            s_nsq[c] = ns;
        }
    };

    float4 bufA[4], bufB[4];
    {
        const float4* s = base + w * 256;
#pragma unroll
        for (int t = 0; t < 4; t++) bufA[t] = s[lane + 64 * t];
    }
#pragma unroll 1
    for (int i = 0; i < 16; i += 2) {
        const int c0 = w + 4 * i;
        {   // prefetch row c0+4 while computing c0
            const float4* s = base + (c0 + 4) * 256;
#pragma unroll
            for (int t = 0; t < 4; t++) bufB[t] = s[lane + 64 * t];
        }
        compute_row(bufA, c0);
        if (i < 14) {   // prefetch row c0+8 while computing c0+4
            const float4* s = base + (c0 + 8) * 256;
#pragma unroll
            for (int t = 0; t < 4; t++) bufA[t] = s[lane + 64 * t];
        }
        compute_row(bufB, c0 + 4);
    }
    __syncthreads();

    // ---- per-wave loss terms ----
    if (w == 0) {
        // contrastive: 12 (anchor, positive) pairs, 20 negatives each
        float ce = 0.0f;
        if (lane < 12) {
            int k = lane / 3;
            int r = lane % 3;
            int m = r + ((r >= k) ? 1 : 0); // r-th column != k
            float nk = fmaxf(sqrtf(s_nsq[act[k]]), 1e-12f);
            float nm = fmaxf(sqrtf(s_nsq[act[m]]), 1e-12f);
            float posv = s_dots[act[k]][m] / (nk * nm) * INV_TEMP;
            float neg[20];
            float mx = posv;
            int base2 = r * 20;
#pragma unroll
            for (int t = 0; t < 20; t++) {
                int c = s_inact[base2 + t];
                float nc = fmaxf(sqrtf(s_nsq[c]), 1e-12f);
                neg[t] = s_dots[c][k] / (nk * nc) * INV_TEMP;
                mx = fmaxf(mx, neg[t]);
            }
            float sum = __expf(posv - mx);
#pragma unroll
            for (int t = 0; t < 20; t++) sum += __expf(neg[t] - mx);
            ce = logf(sum) + mx - posv;
        }
        ce = wred(ce);
        if (lane == 0) s_part[0] = ce;
    } else if (w == 1) {
        // score (BCE), margin, top-k
        float sc = l_lane ? -logf(p_lane) : -log1pf(-p_lane);
        sc = wred(sc);
        float s1 = wred(l_lane ? p_lane : 0.0f); // sum over active
        float s2 = wred(p_lane);                 // total sum
        // top-4 via 4 argmax rounds (tie -> lower index, matches lax.top_k)
        float pv = p_lane;
        int inter = 0;
#pragma unroll
        for (int it = 0; it < 4; it++) {
            float v = pv;
            int   ix = lane;
#pragma unroll
            for (int off = 32; off > 0; off >>= 1) {
                float ov = __shfl_xor(v, off, 64);
                int   oi = __shfl_xor(ix, off, 64);
                if (ov > v || (ov == v && oi < ix)) { v = ov; ix = oi; }
            }
            if (lane == ix) pv = -1e30f;
            if ((mask >> ix) & 1ull) inter++;
        }
        if (lane == 0) {
            s_part[1] = sc;
            float am = s1 * (1.0f / 4.0f);
            float im = (s2 - s1) * (1.0f / 60.0f);
            s_part[2] = fmaxf(MARGIN_C - (am - im), 0.0f);
            float fi = (float)inter;
            float un = (float)(8 - inter);
            s_part[3] = 1.0f - fi / (un + 1e-8f);
        }
    } else if (w == 2) {
        // spatial: pair_sum = sum_{i,j} m_i m_j dist(i,j), dist computed on the fly
        bool  mj = p_lane > 0.5f;
        float px = s_pos[lane * 3 + 0];
        float py = s_pos[lane * 3 + 1];
        float pz = s_pos[lane * 3 + 2];
        float tj = 0.0f;
        for (int i = 0; i < 64; i++) {
            float dx = s_pos[i * 3 + 0] - px;
            float dy = s_pos[i * 3 + 1] - py;
            float dz = s_pos[i * 3 + 2] - pz;
            float d2 = dx * dx + dy * dy + dz * dz;
            bool on = (i != lane) && (s_p[i] > 0.5f);
            tj += on ? sqrtf(d2) : 0.0f;
        }
        float pair = wred(mj ? tj : 0.0f);
        unsigned long long bal = __ballot(mj);
        int nm = __popcll(bal);
        if (lane == 0) {
            s_part[4] = (nm >= 2) ? pair / fmaxf((float)nm * (float)(nm - 1), 1.0f) : 0.0f;
        }
    } else {
        // network coherence: p^T W p
        float tj = 0.0f;
        for (int i = 0; i < 64; i++) tj += s_p[i] * conn[i * 64 + lane];
        float coh = wred(tj * p_lane);
        if (lane == 0) s_part[5] = -coh * (1.0f / 4096.0f);
    }
    __syncthreads();

    if (tid == 0) {
        // per-row loss contribution (unscaled by 1/B; finalize kernel does that)
        partial[b] = 3.0f * s_part[1] * (1.0f / 64.0f)  // score (per-row mean over C)
                   + s_part[2]                           // margin
                   + 2.0f * s_part[3]                    // topk
                   + s_part[0] * (1.0f / 12.0f)          // contrastive
                   + 0.5f * s_part[4]                    // spatial
                   + 0.5f * s_part[5];                   // network
    }
}

__global__ void finalize_kernel(const float* __restrict__ partial, float* __restrict__ out) {
    __shared__ float sm[4];
    const int tid  = threadIdx.x;
    const int w    = tid >> 6;
    const int lane = tid & 63;
    float s = 0.0f;
    for (int i = tid; i < B_N; i += 256) s += partial[i];
    s = wred(s);
    if (lane == 0) sm[w] = s;
    __syncthreads();
    if (tid == 0) out[0] = (sm[0] + sm[1] + sm[2] + sm[3]) * (1.0f / (float)B_N);
}

extern "C" void kernel_launch(void* const* d_in, const int* in_sizes, int n_in,
                              void* d_out, int out_size, void* d_ws, size_t ws_size,
                              hipStream_t stream) {
    const float* pred = (const float*)d_in[0];
    const int*   lab  = (const int*)d_in[1];
    const float* emb  = (const float*)d_in[2];
    const float* cpos = (const float*)d_in[3];
    const float* conn = (const float*)d_in[4];
    float* out = (float*)d_out;
    float* partial = (float*)d_ws;  // 2048 floats = 8 KB, well within ws_size

    // A/B measurement: two identical, idempotent launches. dur_us delta vs the
    // single-launch run (699.8 us) = one loss_kernel duration.
    loss_kernel<<<B_N, 256, 0, stream>>>(pred, lab, emb, cpos, conn, partial);
    loss_kernel<<<B_N, 256, 0, stream>>>(pred, lab, emb, cpos, conn, partial);
    finalize_kernel<<<1, 256, 0, stream>>>(partial, out);
}

// Round 5
// 677.751 us; speedup vs baseline: 1.2095x; 1.2095x over previous
//
#include <hip/hip_runtime.h>

// Problem constants (match reference)
#define B_N 2048
#define C_N 64
#define D_N 1024
// K_ACTIVE=4, N_POS=12, N_NEG_PER=20
#define MARGIN_C 0.15f
#define INV_TEMP (1.0f / 0.07f)

typedef float v4f __attribute__((ext_vector_type(4)));

__device__ __forceinline__ float wred(float v) {
#pragma unroll
    for (int off = 32; off > 0; off >>= 1) v += __shfl_xor(v, off, 64);
    return v;
}

__device__ __forceinline__ v4f nt_load4(const v4f* p) {
    return __builtin_nontemporal_load(p);
}

// R5: wave w streams CONTIGUOUS rows [16w,16w+16) (one linear 64 KB stream per
// wave instead of 4 KB chunks at 16 KB stride) + nontemporal loads on the
// read-once embedding stream. Measured r3 kernel = 119.9 us vs ~86 us floor.
__global__ __launch_bounds__(256, 4)
void loss_kernel(const float* __restrict__ pred,
                 const int*   __restrict__ lab,
                 const float* __restrict__ emb,
                 const float* __restrict__ cpos,
                 const float* __restrict__ conn,
                 float* __restrict__ partial)
{
    __shared__ v4f   s_frag4[1024];   // 16 KB: the 4 active rows, staged once
    __shared__ float s_p[64];
    __shared__ int   s_inact[60];
    __shared__ float s_dots[64][4];   // dots[c][j] = dot(emb_c, emb_act_j) raw
    __shared__ float s_nsq[64];       // squared norms
    __shared__ float s_pos[192];      // 64 x 3 channel positions
    __shared__ float s_part[6];

    const int tid  = threadIdx.x;
    const int w    = tid >> 6;
    const int lane = tid & 63;
    const int b    = blockIdx.x;

    // ---- preamble: fully parallel ----
    const float p_lane = pred[b * 64 + lane];
    const int   l_lane = lab[b * 64 + lane];
    if (tid >= 64 && tid < 256) s_pos[tid - 64] = cpos[tid - 64];

    const unsigned long long mask = __ballot(l_lane != 0);   // same in all waves
    unsigned long long mtmp = mask;
    int act[4];
#pragma unroll
    for (int j = 0; j < 4; j++) { act[j] = __builtin_ctzll(mtmp); mtmp &= mtmp - 1; }

    // cooperative staging of the 4 active rows into LDS (cached loads: possible L2 hit on re-read)
    const v4f* base = (const v4f*)emb + (long)b * 64 * 256;
#pragma unroll
    for (int k = 0; k < 4; k++) s_frag4[k * 256 + tid] = base[act[k] * 256 + tid];

    if (w == 0) {
        s_p[lane] = p_lane;
        if (!((mask >> lane) & 1ull)) {
            int r = __popcll(~mask & ((1ull << lane) - 1ull));  // rank among inactive
            s_inact[r] = lane;
        }
    }
    __syncthreads();

    // ---- fragments LDS -> registers ----
    v4f frag[4][4];
#pragma unroll
    for (int j = 0; j < 4; j++)
#pragma unroll
        for (int t = 0; t < 4; t++) frag[j][t] = s_frag4[j * 256 + lane + 64 * t];

    // ---- main stream: wave w owns contiguous rows [16w, 16w+16), 1-ahead prefetch ----
    auto compute_row = [&](const v4f* buf, int c) {
        float a0 = 0.f, a1 = 0.f, a2 = 0.f, a3 = 0.f, ns = 0.f;
#pragma unroll
        for (int t = 0; t < 4; t++) {
            v4f u = buf[t];
            ns += u.x * u.x + u.y * u.y + u.z * u.z + u.w * u.w;
            a0 += u.x * frag[0][t].x + u.y * frag[0][t].y + u.z * frag[0][t].z + u.w * frag[0][t].w;
            a1 += u.x * frag[1][t].x + u.y * frag[1][t].y + u.z * frag[1][t].z + u.w * frag[1][t].w;
            a2 += u.x * frag[2][t].x + u.y * frag[2][t].y + u.z * frag[2][t].z + u.w * frag[2][t].w;
            a3 += u.x * frag[3][t].x + u.y * frag[3][t].y + u.z * frag[3][t].z + u.w * frag[3][t].w;
        }
#pragma unroll
        for (int off = 32; off > 0; off >>= 1) {
            a0 += __shfl_xor(a0, off, 64); a1 += __shfl_xor(a1, off, 64);
            a2 += __shfl_xor(a2, off, 64); a3 += __shfl_xor(a3, off, 64);
            ns += __shfl_xor(ns, off, 64);
        }
        if (lane == 0) {
            s_dots[c][0] = a0; s_dots[c][1] = a1; s_dots[c][2] = a2; s_dots[c][3] = a3;
            s_nsq[c] = ns;
        }
    };

    const v4f* wbase = base + (w * 16) * 256;   // wave's contiguous 64 KB region
    v4f bufA[4], bufB[4];
#pragma unroll
    for (int t = 0; t < 4; t++) bufA[t] = nt_load4(wbase + lane + 64 * t);

#pragma unroll 1
    for (int i = 0; i < 16; i += 2) {
        const int c0 = w * 16 + i;
        {   // prefetch row i+1 while computing row i
            const v4f* s = wbase + (i + 1) * 256;
#pragma unroll
            for (int t = 0; t < 4; t++) bufB[t] = nt_load4(s + lane + 64 * t);
        }
        compute_row(bufA, c0);
        if (i < 14) {   // prefetch row i+2 while computing row i+1
            const v4f* s = wbase + (i + 2) * 256;
#pragma unroll
            for (int t = 0; t < 4; t++) bufA[t] = nt_load4(s + lane + 64 * t);
        }
        compute_row(bufB, c0 + 1);
    }
    __syncthreads();

    // ---- per-wave loss terms ----
    if (w == 0) {
        // contrastive: 12 (anchor, positive) pairs, 20 negatives each
        float ce = 0.0f;
        if (lane < 12) {
            int k = lane / 3;
            int r = lane % 3;
            int m = r + ((r >= k) ? 1 : 0); // r-th column != k
            float nk = fmaxf(sqrtf(s_nsq[act[k]]), 1e-12f);
            float nm = fmaxf(sqrtf(s_nsq[act[m]]), 1e-12f);
            float posv = s_dots[act[k]][m] / (nk * nm) * INV_TEMP;
            float neg[20];
            float mx = posv;
            int base2 = r * 20;
#pragma unroll
            for (int t = 0; t < 20; t++) {
                int c = s_inact[base2 + t];
                float nc = fmaxf(sqrtf(s_nsq[c]), 1e-12f);
                neg[t] = s_dots[c][k] / (nk * nc) * INV_TEMP;
                mx = fmaxf(mx, neg[t]);
            }
            float sum = __expf(posv - mx);
#pragma unroll
            for (int t = 0; t < 20; t++) sum += __expf(neg[t] - mx);
            ce = logf(sum) + mx - posv;
        }
        ce = wred(ce);
        if (lane == 0) s_part[0] = ce;
    } else if (w == 1) {
        // score (BCE), margin, top-k
        float sc = l_lane ? -logf(p_lane) : -log1pf(-p_lane);
        sc = wred(sc);
        float s1 = wred(l_lane ? p_lane : 0.0f); // sum over active
        float s2 = wred(p_lane);                 // total sum
        // top-4 via 4 argmax rounds (tie -> lower index, matches lax.top_k)
        float pv = p_lane;
        int inter = 0;
#pragma unroll
        for (int it = 0; it < 4; it++) {
            float v = pv;
            int   ix = lane;
#pragma unroll
            for (int off = 32; off > 0; off >>= 1) {
                float ov = __shfl_xor(v, off, 64);
                int   oi = __shfl_xor(ix, off, 64);
                if (ov > v || (ov == v && oi < ix)) { v = ov; ix = oi; }
            }
            if (lane == ix) pv = -1e30f;
            if ((mask >> ix) & 1ull) inter++;
        }
        if (lane == 0) {
            s_part[1] = sc;
            float am = s1 * (1.0f / 4.0f);
            float im = (s2 - s1) * (1.0f / 60.0f);
            s_part[2] = fmaxf(MARGIN_C - (am - im), 0.0f);
            float fi = (float)inter;
            float un = (float)(8 - inter);
            s_part[3] = 1.0f - fi / (un + 1e-8f);
        }
    } else if (w == 2) {
        // spatial: pair_sum = sum_{i,j} m_i m_j dist(i,j), dist computed on the fly
        bool  mj = p_lane > 0.5f;
        float px = s_pos[lane * 3 + 0];
        float py = s_pos[lane * 3 + 1];
        float pz = s_pos[lane * 3 + 2];
        float tj = 0.0f;
        for (int i = 0; i < 64; i++) {
            float dx = s_pos[i * 3 + 0] - px;
            float dy = s_pos[i * 3 + 1] - py;
            float dz = s_pos[i * 3 + 2] - pz;
            float d2 = dx * dx + dy * dy + dz * dz;
            bool on = (i != lane) && (s_p[i] > 0.5f);
            tj += on ? sqrtf(d2) : 0.0f;
        }
        float pair = wred(mj ? tj : 0.0f);
        unsigned long long bal = __ballot(mj);
        int nm = __popcll(bal);
        if (lane == 0) {
            s_part[4] = (nm >= 2) ? pair / fmaxf((float)nm * (float)(nm - 1), 1.0f) : 0.0f;
        }
    } else {
        // network coherence: p^T W p
        float tj = 0.0f;
        for (int i = 0; i < 64; i++) tj += s_p[i] * conn[i * 64 + lane];
        float coh = wred(tj * p_lane);
        if (lane == 0) s_part[5] = -coh * (1.0f / 4096.0f);
    }
    __syncthreads();

    if (tid == 0) {
        // per-row loss contribution (unscaled by 1/B; finalize kernel does that)
        partial[b] = 3.0f * s_part[1] * (1.0f / 64.0f)  // score (per-row mean over C)
                   + s_part[2]                           // margin
                   + 2.0f * s_part[3]                    // topk
                   + s_part[0] * (1.0f / 12.0f)          // contrastive
                   + 0.5f * s_part[4]                    // spatial
                   + 0.5f * s_part[5];                   // network
    }
}

__global__ void finalize_kernel(const float* __restrict__ partial, float* __restrict__ out) {
    __shared__ float sm[4];
    const int tid  = threadIdx.x;
    const int w    = tid >> 6;
    const int lane = tid & 63;
    float s = 0.0f;
    for (int i = tid; i < B_N; i += 256) s += partial[i];
    s = wred(s);
    if (lane == 0) sm[w] = s;
    __syncthreads();
    if (tid == 0) out[0] = (sm[0] + sm[1] + sm[2] + sm[3]) * (1.0f / (float)B_N);
}

extern "C" void kernel_launch(void* const* d_in, const int* in_sizes, int n_in,
                              void* d_out, int out_size, void* d_ws, size_t ws_size,
                              hipStream_t stream) {
    const float* pred = (const float*)d_in[0];
    const int*   lab  = (const int*)d_in[1];
    const float* emb  = (const float*)d_in[2];
    const float* cpos = (const float*)d_in[3];
    const float* conn = (const float*)d_in[4];
    float* out = (float*)d_out;
    float* partial = (float*)d_ws;  // 2048 floats = 8 KB, well within ws_size

    loss_kernel<<<B_N, 256, 0, stream>>>(pred, lab, emb, cpos, conn, partial);
    finalize_kernel<<<1, 256, 0, stream>>>(partial, out);
}